// Round 1
// baseline (401.278 us; speedup 1.0000x reference)
//
#include <hip/hip_runtime.h>

#define B_ 4
#define C_ 256
#define N_ 4096

typedef short s16x8 __attribute__((ext_vector_type(8)));   // 8 bf16 bit patterns
typedef float f32x4 __attribute__((ext_vector_type(4)));

__device__ __forceinline__ unsigned short f2bf(float f) {
  unsigned u = __builtin_bit_cast(unsigned, f);
  u += 0x7FFFu + ((u >> 16) & 1u);          // round-to-nearest-even
  return (unsigned short)(u >> 16);
}
__device__ __forceinline__ float bf2f(unsigned short h) {
  unsigned u = ((unsigned)h) << 16;
  return __builtin_bit_cast(float, u);
}

// ---------------- kernel 0: split weights into bf16 hi/lo ----------------
__global__ void wsplit_kernel(const float* __restrict__ Wq,
                              const float* __restrict__ Wk,
                              const float* __restrict__ Wv,
                              unsigned short* __restrict__ wqh, unsigned short* __restrict__ wql,
                              unsigned short* __restrict__ wkh, unsigned short* __restrict__ wkl,
                              unsigned short* __restrict__ wvh) {
  int i = blockIdx.x * 256 + threadIdx.x;   // 65536 elements
  float q = Wq[i];
  unsigned short h = f2bf(q);
  wqh[i] = h; wql[i] = f2bf(q - bf2f(h));
  float k = Wk[i];
  h = f2bf(k);
  wkh[i] = h; wkl[i] = f2bf(k - bf2f(h));
  wvh[i] = f2bf(Wv[i]);                      // V path: single-pass bf16 is enough
}

// ---------------- kernel 1: QKV projection (1x1 conv) via MFMA ----------------
// grid (64 n-tiles, 4 o-tiles, 12 = b*3+m). m: 0=Q, 1=K (hi/lo split, output [B][N][C]),
// 2=V (single pass, output [B][C][N]).
__global__ __launch_bounds__(256) void proj_kernel(
    const float* __restrict__ x,
    const unsigned short* __restrict__ wqh, const unsigned short* __restrict__ wql,
    const unsigned short* __restrict__ wkh, const unsigned short* __restrict__ wkl,
    const unsigned short* __restrict__ wvh,
    const float* __restrict__ bq, const float* __restrict__ bk, const float* __restrict__ bv,
    unsigned short* __restrict__ Qh, unsigned short* __restrict__ Ql,
    unsigned short* __restrict__ Kh, unsigned short* __restrict__ Kl,
    unsigned short* __restrict__ Vv) {
  __shared__ float lds[256 * 68];   // v: [256 c][68 n-pad]; q/k: transposed [64 n][260 c-pad]

  const int t = threadIdx.x;
  const int n0 = blockIdx.x * 64;
  const int o0 = blockIdx.y * 64;
  const int z = blockIdx.z;
  const int b = z / 3, mm = z % 3;
  const float* xb = x + (size_t)b * C_ * N_ + n0;

  if (mm < 2) {
    // stage x tile transposed: lds[n*260 + c]  (row stride 260 f32 = 1040 B, 16B aligned)
    #pragma unroll
    for (int it = 0; it < 16; ++it) {
      int c = (t >> 4) + (it << 4);
      int n4 = (t & 15) << 2;
      f32x4 v4 = *(const f32x4*)(xb + (size_t)c * N_ + n4);
      lds[(n4 + 0) * 260 + c] = v4.x;
      lds[(n4 + 1) * 260 + c] = v4.y;
      lds[(n4 + 2) * 260 + c] = v4.z;
      lds[(n4 + 3) * 260 + c] = v4.w;
    }
  } else {
    // natural layout: lds[c*68 + n]
    #pragma unroll
    for (int it = 0; it < 16; ++it) {
      int c = (t >> 4) + (it << 4);
      int n4 = (t & 15) << 2;
      *(f32x4*)(lds + c * 68 + n4) = *(const f32x4*)(xb + (size_t)c * N_ + n4);
    }
  }
  __syncthreads();

  const int wv = t >> 6, lane = t & 63, l15 = lane & 15, lg = lane >> 4;
  const f32x4 zero4 = {0.f, 0.f, 0.f, 0.f};

  if (mm < 2) {
    const unsigned short* wh = (mm == 0) ? wqh : wkh;
    const unsigned short* wl = (mm == 0) ? wql : wkl;
    const float* bias = (mm == 0) ? bq : bk;
    unsigned short* Oh = (mm == 0) ? Qh : Kh;
    unsigned short* Ol = (mm == 0) ? Ql : Kl;

    f32x4 acc[4];
    #pragma unroll
    for (int s = 0; s < 4; ++s) acc[s] = zero4;

    #pragma unroll
    for (int cs = 0; cs < 8; ++cs) {
      int c0 = cs * 32 + lg * 8;
      // A fragment: xT rows = n (this wave's 16 rows), 8 consecutive c
      const float* ap = lds + (wv * 16 + l15) * 260 + c0;
      float a[8];
      *(f32x4*)a       = *(const f32x4*)ap;
      *(f32x4*)(a + 4) = *(const f32x4*)(ap + 4);
      s16x8 ahi, alo;
      #pragma unroll
      for (int e = 0; e < 8; ++e) {
        unsigned short h = f2bf(a[e]);
        ahi[e] = (short)h;
        alo[e] = (short)f2bf(a[e] - bf2f(h));
      }
      #pragma unroll
      for (int s = 0; s < 4; ++s) {
        int o = o0 + s * 16 + l15;
        s16x8 bhi = *(const s16x8*)(wh + o * 256 + c0);
        s16x8 blo = *(const s16x8*)(wl + o * 256 + c0);
        acc[s] = __builtin_amdgcn_mfma_f32_16x16x32_bf16(ahi, bhi, acc[s], 0, 0, 0);
        acc[s] = __builtin_amdgcn_mfma_f32_16x16x32_bf16(alo, bhi, acc[s], 0, 0, 0);
        acc[s] = __builtin_amdgcn_mfma_f32_16x16x32_bf16(ahi, blo, acc[s], 0, 0, 0);
      }
    }
    // epilogue: +bias, split hi/lo, store transposed layout [B][N][C]
    #pragma unroll
    for (int s = 0; s < 4; ++s) {
      int o = o0 + s * 16 + l15;
      float bb = bias[o];
      #pragma unroll
      for (int r = 0; r < 4; ++r) {
        int n = n0 + wv * 16 + lg * 4 + r;
        float qf = acc[s][r] + bb;
        unsigned short h = f2bf(qf);
        unsigned short lo = f2bf(qf - bf2f(h));
        size_t idx = ((size_t)(b * N_ + n)) * C_ + o;
        Oh[idx] = h;
        Ol[idx] = lo;
      }
    }
  } else {
    f32x4 acc[4];
    #pragma unroll
    for (int s = 0; s < 4; ++s) acc[s] = zero4;

    #pragma unroll
    for (int cs = 0; cs < 8; ++cs) {
      int c0 = cs * 32 + lg * 8;
      int o = o0 + wv * 16 + l15;
      s16x8 ahi = *(const s16x8*)(wvh + o * 256 + c0);   // A = W rows (contiguous c)
      #pragma unroll
      for (int s = 0; s < 4; ++s) {
        s16x8 bh;
        #pragma unroll
        for (int e = 0; e < 8; ++e)
          bh[e] = (short)f2bf(lds[(c0 + e) * 68 + s * 16 + l15]);
        acc[s] = __builtin_amdgcn_mfma_f32_16x16x32_bf16(ahi, bh, acc[s], 0, 0, 0);
      }
    }
    // epilogue: +bias, store natural layout [B][C][N]
    #pragma unroll
    for (int r = 0; r < 4; ++r) {
      int o = o0 + wv * 16 + lg * 4 + r;
      float bb = bv[o];
      #pragma unroll
      for (int s = 0; s < 4; ++s) {
        float vf = acc[s][r] + bb;
        int n = n0 + s * 16 + l15;
        Vv[((size_t)(b * C_ + o)) * N_ + n] = f2bf(vf);
      }
    }
  }
}

// ---------------- kernel 2: fused flash attention + residual ----------------
// grid (64 i-tiles, 4 batches), 256 threads = 4 waves, wave owns 16 query rows.
// Q (hi/lo) register-resident; K(hi/lo)/V tiles of 64 j staged in XOR-swizzled LDS.
__global__ __launch_bounds__(256, 1) void attn_kernel(
    const unsigned short* __restrict__ Qh, const unsigned short* __restrict__ Ql,
    const unsigned short* __restrict__ Kh, const unsigned short* __restrict__ Kl,
    const unsigned short* __restrict__ Vv,
    const float* __restrict__ x, const float* __restrict__ gamma,
    float* __restrict__ out) {
  __shared__ unsigned short khL[64 * 256];   // [j][c], row 512 B, swizzled
  __shared__ unsigned short klL[64 * 256];
  __shared__ unsigned short vtL[256 * 64];   // [c][j], row 128 B, swizzled
  __shared__ unsigned short pL[4][16 * 72];  // per-wave P[i][j], row stride 72 bf16

  const int t = threadIdx.x, wv = t >> 6, lane = t & 63, l15 = lane & 15, lg = lane >> 4;
  const int i0 = blockIdx.x * 64;
  const int b = blockIdx.y;
  const f32x4 zero4 = {0.f, 0.f, 0.f, 0.f};

  // preload Q fragments: 16 rows (this wave), full C=256 in 8 k-steps, hi+lo
  const int i_row = i0 + wv * 16 + l15;
  const unsigned short* qbh = Qh + ((size_t)(b * N_ + i_row)) * C_ + lg * 8;
  const unsigned short* qbl = Ql + ((size_t)(b * N_ + i_row)) * C_ + lg * 8;
  s16x8 qh[8], ql[8];
  #pragma unroll
  for (int cs = 0; cs < 8; ++cs) {
    qh[cs] = *(const s16x8*)(qbh + cs * 32);
    ql[cs] = *(const s16x8*)(qbl + cs * 32);
  }

  f32x4 oacc[16];
  #pragma unroll
  for (int ct = 0; ct < 16; ++ct) oacc[ct] = zero4;
  float mrow[4] = {-1e30f, -1e30f, -1e30f, -1e30f};
  float lrow[4] = {0.f, 0.f, 0.f, 0.f};

  const char* khg = (const char*)(Kh + ((size_t)(b * N_)) * C_);
  const char* klg = (const char*)(Kl + ((size_t)(b * N_)) * C_);
  const char* vg  = (const char*)(Vv + (size_t)b * C_ * N_);

  for (int jt = 0; jt < 64; ++jt) {
    const int j0 = jt * 64;

    // ---- issue global loads for this K/V tile (held in regs across barrier) ----
    s16x8 rk[8], rl[8], rv[8];
    #pragma unroll
    for (int p = 0; p < 8; ++p) {
      int flat = p * 4096 + t * 16;                // byte offset within 32 KB tile
      int j = flat >> 9, cb = flat & 511;
      size_t goff = (size_t)(j0 + j) * 512 + cb;   // K tile rows are contiguous [N][C]
      rk[p] = *(const s16x8*)(khg + goff);
      rl[p] = *(const s16x8*)(klg + goff);
      int c = flat >> 7, jb = flat & 127;
      rv[p] = *(const s16x8*)(vg + (size_t)c * 8192 + (size_t)j0 * 2 + jb);
    }
    __syncthreads();   // previous iteration's LDS reads complete
    #pragma unroll
    for (int p = 0; p < 8; ++p) {
      int flat = p * 4096 + t * 16;
      int j = flat >> 9, cb = flat & 511;
      int a = j * 512 + (cb ^ ((j & 7) << 4));     // XOR swizzle: bank-conflict-free reads
      *(s16x8*)((char*)khL + a) = rk[p];
      *(s16x8*)((char*)klL + a) = rl[p];
      int c = flat >> 7, jb = flat & 127;
      int av = c * 128 + (jb ^ ((c & 7) << 4));
      *(s16x8*)((char*)vtL + av) = rv[p];
    }
    __syncthreads();

    // ---- S = Q.K (3-pass hi/lo split, fp32 accumulate) ----
    f32x4 sacc[4];
    #pragma unroll
    for (int s = 0; s < 4; ++s) sacc[s] = zero4;
    #pragma unroll
    for (int cs = 0; cs < 8; ++cs) {
      int cb = cs * 64 + lg * 16;                  // byte offset of this lane's c-run
      #pragma unroll
      for (int s = 0; s < 4; ++s) {
        int j = s * 16 + l15;
        int a = j * 512 + (cb ^ ((j & 7) << 4));
        s16x8 kh8 = *(const s16x8*)((const char*)khL + a);
        s16x8 kl8 = *(const s16x8*)((const char*)klL + a);
        sacc[s] = __builtin_amdgcn_mfma_f32_16x16x32_bf16(qh[cs], kh8, sacc[s], 0, 0, 0);
        sacc[s] = __builtin_amdgcn_mfma_f32_16x16x32_bf16(ql[cs], kh8, sacc[s], 0, 0, 0);
        sacc[s] = __builtin_amdgcn_mfma_f32_16x16x32_bf16(qh[cs], kl8, sacc[s], 0, 0, 0);
      }
    }

    // ---- online softmax (rows = lg*4+r; reduce over 16 j-lanes + 4 subtiles) ----
    float p4[4][4];
    float corr[4];
    #pragma unroll
    for (int r = 0; r < 4; ++r) {
      float tm = fmaxf(fmaxf(sacc[0][r], sacc[1][r]), fmaxf(sacc[2][r], sacc[3][r]));
      tm = fmaxf(tm, __shfl_xor(tm, 1));
      tm = fmaxf(tm, __shfl_xor(tm, 2));
      tm = fmaxf(tm, __shfl_xor(tm, 4));
      tm = fmaxf(tm, __shfl_xor(tm, 8));
      float mn = fmaxf(mrow[r], tm);
      float co = __expf(mrow[r] - mn);
      float ps = 0.f;
      #pragma unroll
      for (int s = 0; s < 4; ++s) {
        float pv = __expf(sacc[s][r] - mn);
        p4[s][r] = pv;
        ps += pv;
      }
      ps += __shfl_xor(ps, 1);
      ps += __shfl_xor(ps, 2);
      ps += __shfl_xor(ps, 4);
      ps += __shfl_xor(ps, 8);
      lrow[r] = lrow[r] * co + ps;
      mrow[r] = mn;
      corr[r] = co;
    }
    #pragma unroll
    for (int ct = 0; ct < 16; ++ct) {
      #pragma unroll
      for (int r = 0; r < 4; ++r) oacc[ct][r] *= corr[r];
    }

    // ---- transpose P into A-fragment layout via wave-private LDS ----
    unsigned short* pw = &pL[wv][0];
    #pragma unroll
    for (int s = 0; s < 4; ++s) {
      #pragma unroll
      for (int r = 0; r < 4; ++r)
        pw[(lg * 4 + r) * 72 + s * 16 + l15] = f2bf(p4[s][r]);
    }

    // ---- O += P.V ----
    #pragma unroll
    for (int ks = 0; ks < 2; ++ks) {
      s16x8 pa = *(const s16x8*)(pw + l15 * 72 + ks * 32 + lg * 8);
      #pragma unroll
      for (int ct = 0; ct < 16; ++ct) {
        int c = ct * 16 + l15;
        int jb = ks * 64 + lg * 16;
        int av = c * 128 + (jb ^ ((c & 7) << 4));
        s16x8 vb = *(const s16x8*)((const char*)vtL + av);
        oacc[ct] = __builtin_amdgcn_mfma_f32_16x16x32_bf16(pa, vb, oacc[ct], 0, 0, 0);
      }
    }
  }

  // ---- epilogue: out = gamma * O/l + x ----
  float g = gamma[0];
  #pragma unroll
  for (int r = 0; r < 4; ++r) {
    float inv = 1.f / lrow[r];
    int i = i0 + wv * 16 + lg * 4 + r;
    #pragma unroll
    for (int ct = 0; ct < 16; ++ct) {
      int c = ct * 16 + l15;
      size_t idx = ((size_t)(b * C_ + c)) * N_ + i;
      out[idx] = g * (oacc[ct][r] * inv) + x[idx];
    }
  }
}

extern "C" void kernel_launch(void* const* d_in, const int* in_sizes, int n_in,
                              void* d_out, int out_size, void* d_ws, size_t ws_size,
                              hipStream_t stream) {
  const float* x     = (const float*)d_in[0];
  const float* Wq    = (const float*)d_in[1];
  const float* bq    = (const float*)d_in[2];
  const float* Wk    = (const float*)d_in[3];
  const float* bk    = (const float*)d_in[4];
  const float* Wv    = (const float*)d_in[5];
  const float* bv    = (const float*)d_in[6];
  const float* gamma = (const float*)d_in[7];
  float* out = (float*)d_out;

  unsigned short* ws = (unsigned short*)d_ws;
  const size_t SZ = (size_t)B_ * N_ * C_;       // 4,194,304 elements per tensor
  unsigned short* Qh = ws;
  unsigned short* Ql = ws + SZ;
  unsigned short* Kh = ws + 2 * SZ;
  unsigned short* Kl = ws + 3 * SZ;
  unsigned short* Vv = ws + 4 * SZ;
  unsigned short* wqh = ws + 5 * SZ;            // +5*65536 shorts of weight splits
  unsigned short* wql = wqh + 65536;
  unsigned short* wkh = wqh + 2 * 65536;
  unsigned short* wkl = wqh + 3 * 65536;
  unsigned short* wvh = wqh + 4 * 65536;

  wsplit_kernel<<<dim3(256), 256, 0, stream>>>(Wq, Wk, Wv, wqh, wql, wkh, wkl, wvh);
  proj_kernel<<<dim3(64, 4, 12), 256, 0, stream>>>(x, wqh, wql, wkh, wkl, wvh,
                                                   bq, bk, bv, Qh, Ql, Kh, Kl, Vv);
  attn_kernel<<<dim3(64, 4), 256, 0, stream>>>(Qh, Ql, Kh, Kl, Vv, x, gamma, out);
}